// Round 1
// baseline (276.320 us; speedup 1.0000x reference)
//
#include <hip/hip_runtime.h>

// out[i] = max over 8 contiguous floats of feat[i*8 .. i*8+8)
__global__ void base_max_kernel(const float* __restrict__ feat,
                                float* __restrict__ out, int n) {
    int stride = gridDim.x * blockDim.x;
    for (int i = blockIdx.x * blockDim.x + threadIdx.x; i < n; i += stride) {
        const float4* p = reinterpret_cast<const float4*>(feat + (size_t)i * 8);
        float4 a = p[0];
        float4 b = p[1];
        float m = fmaxf(fmaxf(fmaxf(a.x, a.y), fmaxf(a.z, a.w)),
                        fmaxf(fmaxf(b.x, b.y), fmaxf(b.z, b.w)));
        out[i] = m;
    }
}

// For each face (f1,f2): out[f1,c] = out[f2,c] = max(out[f1,c], out[f2,c])
// One thread handles 4 channels (float4); 8 threads per face; C = 32.
// Face indices are all distinct (arange), so no write conflicts.
__global__ void face_share_kernel(const int* __restrict__ faces,
                                  float* __restrict__ out, int n_faces) {
    int total = n_faces * 8;
    int stride = gridDim.x * blockDim.x;
    for (int t = blockIdx.x * blockDim.x + threadIdx.x; t < total; t += stride) {
        int face = t >> 3;
        int c4   = (t & 7) << 2;
        size_t f1 = (size_t)faces[2 * face];
        size_t f2 = (size_t)faces[2 * face + 1];
        float* p1 = out + f1 * 32 + c4;
        float* p2 = out + f2 * 32 + c4;
        float4 v1 = *reinterpret_cast<const float4*>(p1);
        float4 v2 = *reinterpret_cast<const float4*>(p2);
        float4 s;
        s.x = fmaxf(v1.x, v2.x);
        s.y = fmaxf(v1.y, v2.y);
        s.z = fmaxf(v1.z, v2.z);
        s.w = fmaxf(v1.w, v2.w);
        *reinterpret_cast<float4*>(p1) = s;
        *reinterpret_cast<float4*>(p2) = s;
    }
}

extern "C" void kernel_launch(void* const* d_in, const int* in_sizes, int n_in,
                              void* d_out, int out_size, void* d_ws, size_t ws_size,
                              hipStream_t stream) {
    const float* feat  = (const float*)d_in[0];   // (1e6, 32, 8) f32
    const int*   faces = (const int*)d_in[1];     // (400000, 2) i32
    float* out = (float*)d_out;                   // (1e6, 32) f32

    const int n_base  = out_size;                 // 32,000,000 (tet, c) pairs
    const int n_faces = in_sizes[1] / 2;          // 400,000

    const int block = 256;
    // Memory-bound streaming: capped grid + grid-stride loop.
    int grid_a = min((n_base + block - 1) / block, 4096);
    base_max_kernel<<<grid_a, block, 0, stream>>>(feat, out, n_base);

    int grid_b = min((n_faces * 8 + block - 1) / block, 4096);
    face_share_kernel<<<grid_b, block, 0, stream>>>(faces, out, n_faces);
}

// Round 2
// 249.353 us; speedup vs baseline: 1.1081x; 1.1081x over previous
//
#include <hip/hip_runtime.h>

// ---------- fused path (uses d_ws for partner map) ----------

__global__ void partner_init_kernel(int* __restrict__ partner, int n) {
    int stride = gridDim.x * blockDim.x;
    for (int i = blockIdx.x * blockDim.x + threadIdx.x; i < n; i += stride)
        partner[i] = -1;
}

__global__ void partner_build_kernel(const int* __restrict__ faces,
                                     int* __restrict__ partner, int n_faces) {
    int stride = gridDim.x * blockDim.x;
    for (int f = blockIdx.x * blockDim.x + threadIdx.x; f < n_faces; f += stride) {
        int a = faces[2 * f];
        int b = faces[2 * f + 1];
        partner[a] = b;
        partner[b] = a;
    }
}

// One thread per (tet, channel) output element. t = row*32 + c.
// Reads its own 8 floats (32 B contiguous); if the row has a face partner,
// also reads the partner row's same channel and maxes. Writes one float.
__global__ void fused_pool_kernel(const float* __restrict__ feat,
                                  const int* __restrict__ partner,
                                  float* __restrict__ out, int n) {
    int stride = gridDim.x * blockDim.x;
    for (int t = blockIdx.x * blockDim.x + threadIdx.x; t < n; t += stride) {
        const float4* p = reinterpret_cast<const float4*>(feat + (size_t)t * 8);
        float4 a = p[0];
        float4 b = p[1];
        float m = fmaxf(fmaxf(fmaxf(a.x, a.y), fmaxf(a.z, a.w)),
                        fmaxf(fmaxf(b.x, b.y), fmaxf(b.z, b.w)));
        int row = t >> 5;
        int pr  = partner[row];
        if (pr >= 0) {
            int c = t & 31;
            const float4* q =
                reinterpret_cast<const float4*>(feat + ((size_t)pr * 32 + c) * 8);
            float4 x = q[0];
            float4 y = q[1];
            float m2 = fmaxf(fmaxf(fmaxf(x.x, x.y), fmaxf(x.z, x.w)),
                             fmaxf(fmaxf(y.x, y.y), fmaxf(y.z, y.w)));
            m = fmaxf(m, m2);
        }
        out[t] = m;
    }
}

// ---------- fallback path (no workspace needed) ----------

__global__ void base_max_kernel(const float* __restrict__ feat,
                                float* __restrict__ out, int n) {
    int stride = gridDim.x * blockDim.x;
    for (int i = blockIdx.x * blockDim.x + threadIdx.x; i < n; i += stride) {
        const float4* p = reinterpret_cast<const float4*>(feat + (size_t)i * 8);
        float4 a = p[0];
        float4 b = p[1];
        float m = fmaxf(fmaxf(fmaxf(a.x, a.y), fmaxf(a.z, a.w)),
                        fmaxf(fmaxf(b.x, b.y), fmaxf(b.z, b.w)));
        out[i] = m;
    }
}

__global__ void face_share_kernel(const int* __restrict__ faces,
                                  float* __restrict__ out, int n_faces) {
    int total = n_faces * 8;
    int stride = gridDim.x * blockDim.x;
    for (int t = blockIdx.x * blockDim.x + threadIdx.x; t < total; t += stride) {
        int face = t >> 3;
        int c4   = (t & 7) << 2;
        size_t f1 = (size_t)faces[2 * face];
        size_t f2 = (size_t)faces[2 * face + 1];
        float* p1 = out + f1 * 32 + c4;
        float* p2 = out + f2 * 32 + c4;
        float4 v1 = *reinterpret_cast<const float4*>(p1);
        float4 v2 = *reinterpret_cast<const float4*>(p2);
        float4 s;
        s.x = fmaxf(v1.x, v2.x);
        s.y = fmaxf(v1.y, v2.y);
        s.z = fmaxf(v1.z, v2.z);
        s.w = fmaxf(v1.w, v2.w);
        *reinterpret_cast<float4*>(p1) = s;
        *reinterpret_cast<float4*>(p2) = s;
    }
}

extern "C" void kernel_launch(void* const* d_in, const int* in_sizes, int n_in,
                              void* d_out, int out_size, void* d_ws, size_t ws_size,
                              hipStream_t stream) {
    const float* feat  = (const float*)d_in[0];   // (1e6, 32, 8) f32
    const int*   faces = (const int*)d_in[1];     // (400000, 2) i32
    float* out = (float*)d_out;                   // (1e6, 32) f32

    const int n_elems = out_size;                 // 32,000,000
    const int n_rows  = out_size / 32;            // 1,000,000
    const int n_faces = in_sizes[1] / 2;          // 400,000

    const int block = 256;
    const size_t partner_bytes = (size_t)n_rows * sizeof(int);

    if (ws_size >= partner_bytes) {
        int* partner = (int*)d_ws;

        int grid_i = min((n_rows + block - 1) / block, 2048);
        partner_init_kernel<<<grid_i, block, 0, stream>>>(partner, n_rows);

        int grid_f = min((n_faces + block - 1) / block, 2048);
        partner_build_kernel<<<grid_f, block, 0, stream>>>(faces, partner, n_faces);

        int grid_m = min((n_elems + block - 1) / block, 4096);
        fused_pool_kernel<<<grid_m, block, 0, stream>>>(feat, partner, out, n_elems);
    } else {
        int grid_a = min((n_elems + block - 1) / block, 4096);
        base_max_kernel<<<grid_a, block, 0, stream>>>(feat, out, n_elems);

        int grid_b = min((n_faces * 8 + block - 1) / block, 4096);
        face_share_kernel<<<grid_b, block, 0, stream>>>(faces, out, n_faces);
    }
}